// Round 2
// baseline (106.130 us; speedup 1.0000x reference)
//
#include <hip/hip_runtime.h>
#include <hip/hip_bf16.h>

// Bilinear CNN pooling: dotted[b,c,d] = sum_x L[b,x,c]*R[b,x,d]  (B=32, X=12544, C=128)
// then signed-sqrt + global L2-normalize per batch.
//
// Round 2: conflict-free LDS staging (b128 both sides), RNE-hi/trunc-lo split via
// bit ops + v_perm, BK=32 per barrier pair, NK=28 chunks for occupancy.

#define NK      28            // K-chunks per batch (12544 = 28 * 448)
#define KC      448           // K per chunk
#define BK      32            // K per barrier pair (2 MFMA k-steps)
#define NSTEP   14            // KC / BK
#define BATCH   32
#define CDIM    128
#define XDIM    12544

typedef __bf16 bf16x8 __attribute__((ext_vector_type(8)));
typedef float  f32x16 __attribute__((ext_vector_type(16)));

// 56 MB partial buffer + per-segment sumsq. Fully rewritten before being read
// every launch -> no cross-call state.
__device__ float g_part[(size_t)NK * BATCH * CDIM * CDIM];
__device__ float g_ssq[BATCH * 16];

// Split f into RNE-bf16 hi + truncated-bf16 lo, packed 8-wide into uint4s.
__device__ __forceinline__ void split_pack(const float* f, uint4& hi, uint4& lo) {
  uint xh[8]; uint xl[8];
#pragma unroll
  for (int i = 0; i < 8; ++i) {
    uint u = __float_as_uint(f[i]);
    uint r = u + 0x7FFFu + ((u >> 16) & 1u);        // RNE bf16 in top 16 bits
    xh[i] = r;
    float hif = __uint_as_float(r & 0xFFFF0000u);    // exact hi value
    xl[i] = __float_as_uint(f[i] - hif);             // lo, truncated to bf16 on pack
  }
  hi.x = __builtin_amdgcn_perm(xh[1], xh[0], 0x07060302u);
  hi.y = __builtin_amdgcn_perm(xh[3], xh[2], 0x07060302u);
  hi.z = __builtin_amdgcn_perm(xh[5], xh[4], 0x07060302u);
  hi.w = __builtin_amdgcn_perm(xh[7], xh[6], 0x07060302u);
  lo.x = __builtin_amdgcn_perm(xl[1], xl[0], 0x07060302u);
  lo.y = __builtin_amdgcn_perm(xl[3], xl[2], 0x07060302u);
  lo.z = __builtin_amdgcn_perm(xl[5], xl[4], 0x07060302u);
  lo.w = __builtin_amdgcn_perm(xl[7], xl[6], 0x07060302u);
}

// ---------------------------------------------------------------------------
// Kernel 1: per (chunk, batch): partial[c][d] = sum_{k in chunk} L[k][c]*R[k][d]
// 512 threads = 8 waves (2 row-blocks x 4 col-blocks of 64x32 via 32x32x16 MFMA).
// LDS: 16B unit for (c, k-half h) at index ((c<<2)+h) ^ ((c>>1)&7)   [512 units]
//   -> staging writes (lanes: consec c, h fixed) and fragment reads (32 consec c
//      x 2 k-halves) both spread exactly 8 lanes per 16B bank group: conflict-free.
// ---------------------------------------------------------------------------
__global__ __launch_bounds__(512, 2)
void bcnn_gemm_kernel(const float* __restrict__ L, const float* __restrict__ R) {
  const int chunk = blockIdx.x;
  const int b     = blockIdx.y;
  const int t     = threadIdx.x;
  const int l     = t & 63;
  const int w     = t >> 6;
  const int wr    = w >> 2;          // 0..1
  const int wc    = w & 3;           // 0..3
  const int lc    = l & 31;
  const int hh    = l >> 5;          // k-half within 16-k step

  __shared__ uint4 sAhi[512];
  __shared__ uint4 sAlo[512];
  __shared__ uint4 sBhi[512];
  __shared__ uint4 sBlo[512];

  // staging: this thread owns (c = t&127, k-half sh = t>>7) of both L and R
  const int sc = t & 127;
  const int sh = t >> 7;             // 0..3  (k = sh*8 .. sh*8+7 within BK)
  const int wu = ((sc << 2) + sh) ^ ((sc >> 1) & 7);

  const size_t gofs = ((size_t)b * XDIM + (size_t)chunk * KC + sh * 8) * CDIM + sc;
  const float* Lp = L + gofs;
  const float* Rp = R + gofs;

  // fragment unit indices (ss=0; XOR with 2 for ss=1)
  const int cA0 = wr * 64 + lc;
  const int cA1 = cA0 + 32;
  const int dB  = wc * 32 + lc;
  const int uA0 = ((cA0 << 2) + hh) ^ ((cA0 >> 1) & 7);
  const int uA1 = ((cA1 << 2) + hh) ^ ((cA1 >> 1) & 7);
  const int uB  = ((dB  << 2) + hh) ^ ((dB  >> 1) & 7);

  f32x16 acc0 = {};
  f32x16 acc1 = {};

  float fl[8], fr[8];
#pragma unroll
  for (int i = 0; i < 8; ++i) { fl[i] = Lp[i * CDIM]; fr[i] = Rp[i * CDIM]; }

  for (int s = 0; s < NSTEP; ++s) {
    __syncthreads();                 // previous iteration's fragment reads done
    uint4 h4, l4;
    split_pack(fl, h4, l4);
    sAhi[wu] = h4; sAlo[wu] = l4;
    split_pack(fr, h4, l4);
    sBhi[wu] = h4; sBlo[wu] = l4;

    // issue next tile's loads; in flight across the whole compute phase
    Lp = (s + 1 < NSTEP) ? Lp + BK * CDIM : L;
    Rp = (s + 1 < NSTEP) ? Rp + BK * CDIM : R;
#pragma unroll
    for (int i = 0; i < 8; ++i) { fl[i] = Lp[i * CDIM]; fr[i] = Rp[i * CDIM]; }

    __syncthreads();                 // tile staged

#pragma unroll
    for (int ss = 0; ss < 2; ++ss) {
      const int x = ss << 1;
      bf16x8 ah0 = *(const bf16x8*)&sAhi[uA0 ^ x];
      bf16x8 al0 = *(const bf16x8*)&sAlo[uA0 ^ x];
      bf16x8 ah1 = *(const bf16x8*)&sAhi[uA1 ^ x];
      bf16x8 al1 = *(const bf16x8*)&sAlo[uA1 ^ x];
      bf16x8 bh  = *(const bf16x8*)&sBhi[uB  ^ x];
      bf16x8 bl  = *(const bf16x8*)&sBlo[uB  ^ x];
      // split-fp32: acc += ah*bh + ah*bl + al*bh   (al*bl ~2^-17 rel, dropped)
      acc0 = __builtin_amdgcn_mfma_f32_32x32x16_bf16(ah0, bh, acc0, 0, 0, 0);
      acc1 = __builtin_amdgcn_mfma_f32_32x32x16_bf16(ah1, bh, acc1, 0, 0, 0);
      acc0 = __builtin_amdgcn_mfma_f32_32x32x16_bf16(ah0, bl, acc0, 0, 0, 0);
      acc1 = __builtin_amdgcn_mfma_f32_32x32x16_bf16(ah1, bl, acc1, 0, 0, 0);
      acc0 = __builtin_amdgcn_mfma_f32_32x32x16_bf16(al0, bh, acc0, 0, 0, 0);
      acc1 = __builtin_amdgcn_mfma_f32_32x32x16_bf16(al1, bh, acc1, 0, 0, 0);
    }
  }

  // C/D layout (HW-validated round 1): col = lane&31, row = (r&3)+8*(r>>2)+4*hh
  float* outp = g_part + (((size_t)chunk * BATCH + b) << 14);
#pragma unroll
  for (int r = 0; r < 16; ++r) {
    const int row = (r & 3) + ((r >> 2) << 3) + (hh << 2);
    outp[(size_t)(wr * 64 + row) * CDIM + (wc * 32 + lc)]      = acc0[r];
    outp[(size_t)(wr * 64 + 32 + row) * CDIM + (wc * 32 + lc)] = acc1[r];
  }
}

// ---------------------------------------------------------------------------
// Kernel 2a: sum NK partials, signed-sqrt, write sqrted, per-segment sumsq.
// grid (16 segs, 32 batches) x 256 threads; float4 per thread.
// ---------------------------------------------------------------------------
__global__ void bcnn_sqrt_kernel(float* __restrict__ out) {
  const int b   = blockIdx.y;
  const int seg = blockIdx.x;
  const int t   = threadIdx.x;
  const int idx = seg * 1024 + t * 4;

  float4 v = {0.f, 0.f, 0.f, 0.f};
#pragma unroll
  for (int ch = 0; ch < NK; ++ch) {
    const float4 p = *(const float4*)&g_part[(((size_t)ch * BATCH + b) << 14) + idx];
    v.x += p.x; v.y += p.y; v.z += p.z; v.w += p.w;
  }
  float4 sv;
  {
    float a;
    a = sqrtf(fabsf(v.x) + 1e-9f); sv.x = (v.x > 0.f) ? a : ((v.x < 0.f) ? -a : 0.f);
    a = sqrtf(fabsf(v.y) + 1e-9f); sv.y = (v.y > 0.f) ? a : ((v.y < 0.f) ? -a : 0.f);
    a = sqrtf(fabsf(v.z) + 1e-9f); sv.z = (v.z > 0.f) ? a : ((v.z < 0.f) ? -a : 0.f);
    a = sqrtf(fabsf(v.w) + 1e-9f); sv.w = (v.w > 0.f) ? a : ((v.w < 0.f) ? -a : 0.f);
  }
  *(float4*)&out[((size_t)b << 14) + idx] = sv;

  float ss = sv.x * sv.x + sv.y * sv.y + sv.z * sv.z + sv.w * sv.w;
#pragma unroll
  for (int o = 32; o > 0; o >>= 1) ss += __shfl_down(ss, o, 64);
  __shared__ float red[4];
  if ((t & 63) == 0) red[t >> 6] = ss;
  __syncthreads();
  if (t == 0) g_ssq[b * 16 + seg] = red[0] + red[1] + red[2] + red[3];
}

// ---------------------------------------------------------------------------
// Kernel 2b: scale by rsqrt(max(sumsq, 1e-12))
// ---------------------------------------------------------------------------
__global__ void bcnn_scale_kernel(float* __restrict__ out) {
  const int b   = blockIdx.y;
  const int seg = blockIdx.x;
  const int t   = threadIdx.x;

  float tot = 0.f;
#pragma unroll
  for (int i = 0; i < 16; ++i) tot += g_ssq[b * 16 + i];
  const float scale = rsqrtf(fmaxf(tot, 1e-12f));

  const size_t base = ((size_t)b << 14) + seg * 1024 + t * 4;
  float4 v = *(float4*)&out[base];
  v.x *= scale; v.y *= scale; v.z *= scale; v.w *= scale;
  *(float4*)&out[base] = v;
}

extern "C" void kernel_launch(void* const* d_in, const int* in_sizes, int n_in,
                              void* d_out, int out_size, void* d_ws, size_t ws_size,
                              hipStream_t stream) {
  const float* L = (const float*)d_in[0];
  const float* R = (const float*)d_in[1];
  float* out = (float*)d_out;

  dim3 g1(NK, BATCH);
  bcnn_gemm_kernel<<<g1, 512, 0, stream>>>(L, R);

  dim3 g2(16, BATCH);
  bcnn_sqrt_kernel<<<g2, 256, 0, stream>>>(out);
  bcnn_scale_kernel<<<g2, 256, 0, stream>>>(out);
}

// Round 3
// 105.310 us; speedup vs baseline: 1.0078x; 1.0078x over previous
//
#include <hip/hip_runtime.h>
#include <hip/hip_bf16.h>

// Bilinear CNN pooling: dotted[b,c,d] = sum_x L[b,x,c]*R[b,x,d]  (B=32, X=12544, C=128)
// then signed-sqrt + global L2-normalize per batch.
//
// Round 3: global_load_lds(16B) raw-f32 staging, 4-buffer 3-deep pipeline with
// counted vmcnt (never drained in main loop), transpose-at-read via ds_read_b32
// (2-way aliasing = free), in-register RNE-hi/trunc-lo bf16 split, NK=16.

#define NK      16            // K-chunks per batch
#define KC      784           // 12544 / 16
#define BK      16            // K per tile
#define NT      49            // KC / BK
#define BATCH   32
#define CDIM    128
#define XDIM    12544

typedef __bf16 bf16x8 __attribute__((ext_vector_type(8)));
typedef float  f32x16 __attribute__((ext_vector_type(16)));

// 32 MB partial buffer + per-segment sumsq; fully rewritten before read each launch.
__device__ float g_part[(size_t)NK * BATCH * CDIM * CDIM];
__device__ float g_ssq[BATCH * 16];

// Split 8 f32 into RNE-bf16 hi + truncated-bf16 lo, packed into uint4s (validated r1/r2).
__device__ __forceinline__ void split8(const float* f, uint4& hi, uint4& lo) {
  uint xh[8]; uint xl[8];
#pragma unroll
  for (int i = 0; i < 8; ++i) {
    uint u = __float_as_uint(f[i]);
    uint r = u + 0x7FFFu + ((u >> 16) & 1u);         // RNE bf16 in top 16 bits
    xh[i] = r;
    float hif = __uint_as_float(r & 0xFFFF0000u);     // exact hi value
    xl[i] = __float_as_uint(f[i] - hif);              // lo (exact sub), trunc on pack
  }
  hi.x = __builtin_amdgcn_perm(xh[1], xh[0], 0x07060302u);
  hi.y = __builtin_amdgcn_perm(xh[3], xh[2], 0x07060302u);
  hi.z = __builtin_amdgcn_perm(xh[5], xh[4], 0x07060302u);
  hi.w = __builtin_amdgcn_perm(xh[7], xh[6], 0x07060302u);
  lo.x = __builtin_amdgcn_perm(xl[1], xl[0], 0x07060302u);
  lo.y = __builtin_amdgcn_perm(xl[3], xl[2], 0x07060302u);
  lo.z = __builtin_amdgcn_perm(xl[5], xl[4], 0x07060302u);
  lo.w = __builtin_amdgcn_perm(xl[7], xl[6], 0x07060302u);
}

// ---------------------------------------------------------------------------
// Kernel 1: per (chunk, batch): partial[c][d] = sum_{k in chunk} L[k][c]*R[k][d]
// 512 threads = 8 waves (2x4 grid of 64x32 tiles, 32x32x16 MFMA, 3-pass split).
// LDS: 4 buffers x (16x128 f32) per matrix, staged linearly by global_load_lds;
// fragments gathered by strided ds_read_b32 (contiguous across lanes).
// ---------------------------------------------------------------------------
__global__ __launch_bounds__(512, 2)
void bcnn_gemm_kernel(const float* __restrict__ L, const float* __restrict__ R) {
  __shared__ float sL[4][BK * CDIM];
  __shared__ float sR[4][BK * CDIM];

  const int chunk = blockIdx.x;
  const int b     = blockIdx.y;
  const int t     = threadIdx.x;
  const int l     = t & 63;
  const int w     = t >> 6;
  const int wr    = w >> 2;          // 0..1
  const int wc    = w & 3;           // 0..3
  const int lc    = l & 31;
  const int hh    = l >> 5;          // k-half selector

  // staging source: tile s is a contiguous 8KB row-block; this thread's 16B at +t*16
  const float* gL = L + ((size_t)b * XDIM + (size_t)chunk * KC) * CDIM + t * 4;
  const float* gR = R + ((size_t)b * XDIM + (size_t)chunk * KC) * CDIM + t * 4;

  const int cA0 = wr * 64 + lc;
  const int cA1 = cA0 + 32;
  const int dB  = wc * 32 + lc;
  const int kbase = hh * 8 * CDIM;

  f32x16 acc0 = {};
  f32x16 acc1 = {};

#define STAGE(s)                                                                   \
  do {                                                                             \
    const float* pL_ = gL + (size_t)(s) * BK * CDIM;                               \
    const float* pR_ = gR + (size_t)(s) * BK * CDIM;                               \
    float* dL_ = &sL[(s) & 3][t * 4];                                              \
    float* dR_ = &sR[(s) & 3][t * 4];                                              \
    __builtin_amdgcn_global_load_lds(                                              \
        (const __attribute__((address_space(1))) unsigned int*)pL_,                \
        (__attribute__((address_space(3))) unsigned int*)dL_, 16, 0, 0);           \
    __builtin_amdgcn_global_load_lds(                                              \
        (const __attribute__((address_space(1))) unsigned int*)pR_,                \
        (__attribute__((address_space(3))) unsigned int*)dR_, 16, 0, 0);           \
  } while (0)

#define COMPUTE(s)                                                                 \
  do {                                                                             \
    const float* bufL_ = sL[(s) & 3];                                              \
    const float* bufR_ = sR[(s) & 3];                                              \
    float fA0[8], fA1[8], fB[8];                                                   \
    _Pragma("unroll")                                                              \
    for (int i = 0; i < 8; ++i) {                                                  \
      fA0[i] = bufL_[kbase + i * CDIM + cA0];                                      \
      fA1[i] = bufL_[kbase + i * CDIM + cA1];                                      \
      fB[i]  = bufR_[kbase + i * CDIM + dB];                                       \
    }                                                                              \
    uint4 h0, l0, h1, l1, hb, lb;                                                  \
    split8(fA0, h0, l0); split8(fA1, h1, l1); split8(fB, hb, lb);                  \
    bf16x8 ah0 = *(bf16x8*)&h0, al0 = *(bf16x8*)&l0;                               \
    bf16x8 ah1 = *(bf16x8*)&h1, al1 = *(bf16x8*)&l1;                               \
    bf16x8 bh  = *(bf16x8*)&hb, bl  = *(bf16x8*)&lb;                               \
    acc0 = __builtin_amdgcn_mfma_f32_32x32x16_bf16(ah0, bh, acc0, 0, 0, 0);        \
    acc1 = __builtin_amdgcn_mfma_f32_32x32x16_bf16(ah1, bh, acc1, 0, 0, 0);        \
    acc0 = __builtin_amdgcn_mfma_f32_32x32x16_bf16(ah0, bl, acc0, 0, 0, 0);        \
    acc1 = __builtin_amdgcn_mfma_f32_32x32x16_bf16(ah1, bl, acc1, 0, 0, 0);        \
    acc0 = __builtin_amdgcn_mfma_f32_32x32x16_bf16(al0, bh, acc0, 0, 0, 0);        \
    acc1 = __builtin_amdgcn_mfma_f32_32x32x16_bf16(al1, bh, acc1, 0, 0, 0);        \
  } while (0)

  // prologue: 3 tiles in flight (6 vmem instrs)
  STAGE(0); STAGE(1); STAGE(2);

  // main loop: one barrier per iter, counted vmcnt — never drained
  for (int s = 0; s < NT - 2; ++s) {
    asm volatile("s_waitcnt vmcnt(4) lgkmcnt(0)" ::: "memory");
    __builtin_amdgcn_s_barrier();
    asm volatile("" ::: "memory");
    if (s + 3 < NT) STAGE(s + 3);
    COMPUTE(s);
  }
  // tail: s = NT-2 (only tile NT-1 still in flight)
  asm volatile("s_waitcnt vmcnt(2) lgkmcnt(0)" ::: "memory");
  __builtin_amdgcn_s_barrier();
  asm volatile("" ::: "memory");
  COMPUTE(NT - 2);
  // tail: s = NT-1
  asm volatile("s_waitcnt vmcnt(0) lgkmcnt(0)" ::: "memory");
  __builtin_amdgcn_s_barrier();
  asm volatile("" ::: "memory");
  COMPUTE(NT - 1);

#undef STAGE
#undef COMPUTE

  // C/D layout (HW-validated r1/r2): col = lane&31, row = (r&3)+8*(r>>2)+4*hh
  float* outp = g_part + (((size_t)chunk * BATCH + b) << 14);
#pragma unroll
  for (int r = 0; r < 16; ++r) {
    const int row = (r & 3) + ((r >> 2) << 3) + (hh << 2);
    outp[(size_t)(wr * 64 + row) * CDIM + (wc * 32 + lc)]      = acc0[r];
    outp[(size_t)(wr * 64 + 32 + row) * CDIM + (wc * 32 + lc)] = acc1[r];
  }
}

// ---------------------------------------------------------------------------
// Kernel 2a: sum NK partials, signed-sqrt, write sqrted, per-segment sumsq.
// grid (16 segs, 32 batches) x 256 threads; float4 per thread.
// ---------------------------------------------------------------------------
__global__ void bcnn_sqrt_kernel(float* __restrict__ out) {
  const int b   = blockIdx.y;
  const int seg = blockIdx.x;
  const int t   = threadIdx.x;
  const int idx = seg * 1024 + t * 4;

  float4 v = {0.f, 0.f, 0.f, 0.f};
#pragma unroll
  for (int ch = 0; ch < NK; ++ch) {
    const float4 p = *(const float4*)&g_part[(((size_t)ch * BATCH + b) << 14) + idx];
    v.x += p.x; v.y += p.y; v.z += p.z; v.w += p.w;
  }
  float4 sv;
  {
    float a;
    a = sqrtf(fabsf(v.x) + 1e-9f); sv.x = (v.x > 0.f) ? a : ((v.x < 0.f) ? -a : 0.f);
    a = sqrtf(fabsf(v.y) + 1e-9f); sv.y = (v.y > 0.f) ? a : ((v.y < 0.f) ? -a : 0.f);
    a = sqrtf(fabsf(v.z) + 1e-9f); sv.z = (v.z > 0.f) ? a : ((v.z < 0.f) ? -a : 0.f);
    a = sqrtf(fabsf(v.w) + 1e-9f); sv.w = (v.w > 0.f) ? a : ((v.w < 0.f) ? -a : 0.f);
  }
  *(float4*)&out[((size_t)b << 14) + idx] = sv;

  float ss = sv.x * sv.x + sv.y * sv.y + sv.z * sv.z + sv.w * sv.w;
#pragma unroll
  for (int o = 32; o > 0; o >>= 1) ss += __shfl_down(ss, o, 64);
  __shared__ float red[4];
  if ((t & 63) == 0) red[t >> 6] = ss;
  __syncthreads();
  if (t == 0) g_ssq[b * 16 + seg] = red[0] + red[1] + red[2] + red[3];
}

// ---------------------------------------------------------------------------
// Kernel 2b: scale by rsqrt(max(sumsq, 1e-12))
// ---------------------------------------------------------------------------
__global__ void bcnn_scale_kernel(float* __restrict__ out) {
  const int b   = blockIdx.y;
  const int seg = blockIdx.x;
  const int t   = threadIdx.x;

  float tot = 0.f;
#pragma unroll
  for (int i = 0; i < 16; ++i) tot += g_ssq[b * 16 + i];
  const float scale = rsqrtf(fmaxf(tot, 1e-12f));

  const size_t base = ((size_t)b << 14) + seg * 1024 + t * 4;
  float4 v = *(float4*)&out[base];
  v.x *= scale; v.y *= scale; v.z *= scale; v.w *= scale;
  *(float4*)&out[base] = v;
}

extern "C" void kernel_launch(void* const* d_in, const int* in_sizes, int n_in,
                              void* d_out, int out_size, void* d_ws, size_t ws_size,
                              hipStream_t stream) {
  const float* L = (const float*)d_in[0];
  const float* R = (const float*)d_in[1];
  float* out = (float*)d_out;

  dim3 g1(NK, BATCH);
  bcnn_gemm_kernel<<<g1, 512, 0, stream>>>(L, R);

  dim3 g2(16, BATCH);
  bcnn_sqrt_kernel<<<g2, 256, 0, stream>>>(out);
  bcnn_scale_kernel<<<g2, 256, 0, stream>>>(out);
}

// Round 4
// 96.178 us; speedup vs baseline: 1.1035x; 1.0950x over previous
//
#include <hip/hip_runtime.h>
#include <hip/hip_bf16.h>

// Bilinear CNN pooling: dotted[b,c,d] = sum_x L[b,x,c]*R[b,x,d]  (B=32, X=12544, C=128)
// then signed-sqrt + global L2-normalize per batch.
//
// Round 4: register-staged loads (compiler-counted vmcnt, raw s_barrier -- no
// vmcnt(0) drain) + stage-time bf16 hi/lo split (each element converted ONCE),
// packed LDS with conflict-free b128 frag reads. 2 sets, 2-tile lookahead.

#define NK      16            // K-chunks per batch
#define KC      784           // 12544 / 16
#define BK      16            // K per tile
#define NT      49            // KC / BK
#define BATCH   32
#define CDIM    128
#define XDIM    12544

typedef __bf16 bf16x8 __attribute__((ext_vector_type(8)));
typedef float  f32x16 __attribute__((ext_vector_type(16)));

// 32 MB partial buffer + per-segment sumsq; fully rewritten before read each launch.
__device__ float g_part[(size_t)NK * BATCH * CDIM * CDIM];
__device__ float g_ssq[BATCH * 16];

// Split 4 f32 -> RNE-bf16 hi + trunc-bf16 lo, packed (validated r1-r3).
__device__ __forceinline__ void split4(const float* f, uint2& hi, uint2& lo) {
  uint xh[4], xl[4];
#pragma unroll
  for (int i = 0; i < 4; ++i) {
    uint u = __float_as_uint(f[i]);
    uint r = u + 0x7FFFu + ((u >> 16) & 1u);       // RNE bf16 in top 16 bits
    xh[i] = r;
    float hif = __uint_as_float(r & 0xFFFF0000u);   // exact hi value
    xl[i] = __float_as_uint(f[i] - hif);            // exact residual, trunc on pack
  }
  hi.x = __builtin_amdgcn_perm(xh[1], xh[0], 0x07060302u);
  hi.y = __builtin_amdgcn_perm(xh[3], xh[2], 0x07060302u);
  lo.x = __builtin_amdgcn_perm(xl[1], xl[0], 0x07060302u);
  lo.y = __builtin_amdgcn_perm(xl[3], xl[2], 0x07060302u);
}

// LDS 16B-unit index for (column c, k-half kh): conflict-free on both sides.
__device__ __forceinline__ int ldsu(int c, int kh) {
  return ((c << 1) | kh) ^ ((c >> 2) & 7);
}

// ---------------------------------------------------------------------------
// Kernel 1: per (chunk, batch): partial[c][d] = sum_{k in chunk} L[k][c]*R[k][d]
// 512 threads = 8 waves (2x4 grid of 64x32 tiles, 32x32x16 MFMA, 3-pass split).
// ---------------------------------------------------------------------------
__global__ __launch_bounds__(512, 4)
void bcnn_gemm_kernel(const float* __restrict__ L, const float* __restrict__ R) {
  // [set][slot]: slot = unit*2 + (h&1); uint2 = 8B; 4KB per array per set
  __shared__ uint2 sAhi[2][512], sAlo[2][512], sBhi[2][512], sBlo[2][512];

  const int chunk = blockIdx.x;
  const int b     = blockIdx.y;
  const int t     = threadIdx.x;
  const int l     = t & 63;
  const int w     = t >> 6;
  const int wr    = w >> 2;          // 0..1
  const int wc    = w & 3;           // 0..3
  const int lc    = l & 31;
  const int hh    = l >> 5;          // k-half selector

  // staging: thread owns column c, k = h*4 + i (i=0..3)
  const int sc = t & 127;
  const int sh = t >> 7;             // 0..3
  const int wslot = ldsu(sc, sh >> 1) * 2 + (sh & 1);

  const float* gL = L + ((size_t)b * XDIM + (size_t)chunk * KC + sh * 4) * CDIM + sc;
  const float* gR = R + ((size_t)b * XDIM + (size_t)chunk * KC + sh * 4) * CDIM + sc;

  // fragment slots
  const int cA0 = wr * 64 + lc;
  const int cA1 = cA0 + 32;
  const int dB  = wc * 32 + lc;
  const int uA0 = ldsu(cA0, hh) * 2;
  const int uA1 = ldsu(cA1, hh) * 2;
  const int uB  = ldsu(dB,  hh) * 2;

  f32x16 acc0 = {};
  f32x16 acc1 = {};

  float rlE[4], rrE[4], rlO[4], rrO[4];   // two static register-parity sets

#define LOADR(rl, rr, s)                                                       \
  do {                                                                         \
    const float* pL_ = gL + (size_t)(s) * BK * CDIM;                           \
    const float* pR_ = gR + (size_t)(s) * BK * CDIM;                           \
    _Pragma("unroll")                                                          \
    for (int i = 0; i < 4; ++i) { rl[i] = pL_[i * CDIM]; rr[i] = pR_[i * CDIM]; } \
  } while (0)

#define WRITE(rl, rr, set)                                                     \
  do {                                                                         \
    uint2 hi_, lo_;                                                            \
    split4(rl, hi_, lo_);                                                      \
    sAhi[set][wslot] = hi_; sAlo[set][wslot] = lo_;                            \
    split4(rr, hi_, lo_);                                                      \
    sBhi[set][wslot] = hi_; sBlo[set][wslot] = lo_;                            \
  } while (0)

#define COMPUTE(set)                                                           \
  do {                                                                         \
    bf16x8 ah0 = *(const bf16x8*)&sAhi[set][uA0];                              \
    bf16x8 al0 = *(const bf16x8*)&sAlo[set][uA0];                              \
    bf16x8 ah1 = *(const bf16x8*)&sAhi[set][uA1];                              \
    bf16x8 al1 = *(const bf16x8*)&sAlo[set][uA1];                              \
    bf16x8 bh  = *(const bf16x8*)&sBhi[set][uB];                               \
    bf16x8 bl  = *(const bf16x8*)&sBlo[set][uB];                               \
    acc0 = __builtin_amdgcn_mfma_f32_32x32x16_bf16(ah0, bh, acc0, 0, 0, 0);    \
    acc1 = __builtin_amdgcn_mfma_f32_32x32x16_bf16(ah1, bh, acc1, 0, 0, 0);    \
    acc0 = __builtin_amdgcn_mfma_f32_32x32x16_bf16(ah0, bl, acc0, 0, 0, 0);    \
    acc1 = __builtin_amdgcn_mfma_f32_32x32x16_bf16(ah1, bl, acc1, 0, 0, 0);    \
    acc0 = __builtin_amdgcn_mfma_f32_32x32x16_bf16(al0, bh, acc0, 0, 0, 0);    \
    acc1 = __builtin_amdgcn_mfma_f32_32x32x16_bf16(al1, bh, acc1, 0, 0, 0);    \
  } while (0)

#define BAR()                                                                  \
  do {                                                                         \
    asm volatile("s_waitcnt lgkmcnt(0)" ::: "memory");                         \
    __builtin_amdgcn_s_barrier();                                              \
  } while (0)

  // prologue: tiles 0,1 in flight; write tile0 (waits its regs, tile1 stays live)
  LOADR(rlE, rrE, 0);
  LOADR(rlO, rrO, 1);
  WRITE(rlE, rrE, 0);
  BAR();

  // steady state, 2-unrolled for static reg parity.
  // iter s: compute set s&1; issue tile s+2 -> reg parity s&1; write tile s+1.
  for (int it = 0; it < 24; ++it) {
    const int s0 = 2 * it;
    // even iter
    LOADR(rlE, rrE, s0 + 2);
    COMPUTE(0);
    WRITE(rlO, rrO, 1);
    BAR();
    // odd iter
    if (s0 + 3 < NT) LOADR(rlO, rrO, s0 + 3);
    COMPUTE(1);
    WRITE(rlE, rrE, 0);
    BAR();
  }
  // final tile s = 48 (set 0)
  COMPUTE(0);

#undef LOADR
#undef WRITE
#undef COMPUTE
#undef BAR

  // C/D layout (HW-validated r1-r3): col = lane&31, row = (r&3)+8*(r>>2)+4*hh
  float* outp = g_part + (((size_t)chunk * BATCH + b) << 14);
#pragma unroll
  for (int r = 0; r < 16; ++r) {
    const int row = (r & 3) + ((r >> 2) << 3) + (hh << 2);
    outp[(size_t)(wr * 64 + row) * CDIM + (wc * 32 + lc)]      = acc0[r];
    outp[(size_t)(wr * 64 + 32 + row) * CDIM + (wc * 32 + lc)] = acc1[r];
  }
}

// ---------------------------------------------------------------------------
// Kernel 2a: sum NK partials, signed-sqrt, write sqrted, per-segment sumsq.
// ---------------------------------------------------------------------------
__global__ void bcnn_sqrt_kernel(float* __restrict__ out) {
  const int b   = blockIdx.y;
  const int seg = blockIdx.x;
  const int t   = threadIdx.x;
  const int idx = seg * 1024 + t * 4;

  float4 v = {0.f, 0.f, 0.f, 0.f};
#pragma unroll
  for (int ch = 0; ch < NK; ++ch) {
    const float4 p = *(const float4*)&g_part[(((size_t)ch * BATCH + b) << 14) + idx];
    v.x += p.x; v.y += p.y; v.z += p.z; v.w += p.w;
  }
  float4 sv;
  {
    float a;
    a = sqrtf(fabsf(v.x) + 1e-9f); sv.x = (v.x > 0.f) ? a : ((v.x < 0.f) ? -a : 0.f);
    a = sqrtf(fabsf(v.y) + 1e-9f); sv.y = (v.y > 0.f) ? a : ((v.y < 0.f) ? -a : 0.f);
    a = sqrtf(fabsf(v.z) + 1e-9f); sv.z = (v.z > 0.f) ? a : ((v.z < 0.f) ? -a : 0.f);
    a = sqrtf(fabsf(v.w) + 1e-9f); sv.w = (v.w > 0.f) ? a : ((v.w < 0.f) ? -a : 0.f);
  }
  *(float4*)&out[((size_t)b << 14) + idx] = sv;

  float ss = sv.x * sv.x + sv.y * sv.y + sv.z * sv.z + sv.w * sv.w;
#pragma unroll
  for (int o = 32; o > 0; o >>= 1) ss += __shfl_down(ss, o, 64);
  __shared__ float red[4];
  if ((t & 63) == 0) red[t >> 6] = ss;
  __syncthreads();
  if (t == 0) g_ssq[b * 16 + seg] = red[0] + red[1] + red[2] + red[3];
}

// ---------------------------------------------------------------------------
// Kernel 2b: scale by rsqrt(max(sumsq, 1e-12))
// ---------------------------------------------------------------------------
__global__ void bcnn_scale_kernel(float* __restrict__ out) {
  const int b   = blockIdx.y;
  const int seg = blockIdx.x;
  const int t   = threadIdx.x;

  float tot = 0.f;
#pragma unroll
  for (int i = 0; i < 16; ++i) tot += g_ssq[b * 16 + i];
  const float scale = rsqrtf(fmaxf(tot, 1e-12f));

  const size_t base = ((size_t)b << 14) + seg * 1024 + t * 4;
  float4 v = *(float4*)&out[base];
  v.x *= scale; v.y *= scale; v.z *= scale; v.w *= scale;
  *(float4*)&out[base] = v;
}

extern "C" void kernel_launch(void* const* d_in, const int* in_sizes, int n_in,
                              void* d_out, int out_size, void* d_ws, size_t ws_size,
                              hipStream_t stream) {
  const float* L = (const float*)d_in[0];
  const float* R = (const float*)d_in[1];
  float* out = (float*)d_out;

  dim3 g1(NK, BATCH);
  bcnn_gemm_kernel<<<g1, 512, 0, stream>>>(L, R);

  dim3 g2(16, BATCH);
  bcnn_sqrt_kernel<<<g2, 256, 0, stream>>>(out);
  bcnn_scale_kernel<<<g2, 256, 0, stream>>>(out);
}

// Round 5
// 92.490 us; speedup vs baseline: 1.1475x; 1.0399x over previous
//
#include <hip/hip_runtime.h>
#include <hip/hip_bf16.h>

// Bilinear CNN pooling: dotted[b,c,d] = sum_x L[b,x,c]*R[b,x,d]  (B=32, X=12544, C=128)
// then signed-sqrt + global L2-normalize per batch.
//
// Round 5: traffic cut. NK=8 (halves partial round-trip to 32 MB), BK=32
// (half the barriers, deeper load pipeline), r4's validated stage-time-split
// register-staged structure otherwise unchanged. 1 block/CU, 8 waves.

#define NK      8             // K-chunks per batch
#define KC      1568          // 12544 / 8
#define BK      32            // K per tile
#define NT      49            // KC / BK
#define BATCH   32
#define CDIM    128
#define XDIM    12544

typedef __bf16 bf16x8 __attribute__((ext_vector_type(8)));
typedef float  f32x16 __attribute__((ext_vector_type(16)));

// 16 MB partial buffer + per-segment sumsq; fully rewritten before read each launch.
__device__ float g_part[(size_t)NK * BATCH * CDIM * CDIM];
__device__ float g_ssq[BATCH * 16];

// Split 8 f32 -> RNE-bf16 hi + trunc-bf16 lo, packed into uint4s (validated r1-r4).
__device__ __forceinline__ void split8(const float* f, uint4& hi, uint4& lo) {
  uint xh[8], xl[8];
#pragma unroll
  for (int i = 0; i < 8; ++i) {
    uint u = __float_as_uint(f[i]);
    uint r = u + 0x7FFFu + ((u >> 16) & 1u);        // RNE bf16 in top 16 bits
    xh[i] = r;
    float hif = __uint_as_float(r & 0xFFFF0000u);    // exact hi value
    xl[i] = __float_as_uint(f[i] - hif);             // exact residual, trunc on pack
  }
  hi.x = __builtin_amdgcn_perm(xh[1], xh[0], 0x07060302u);
  hi.y = __builtin_amdgcn_perm(xh[3], xh[2], 0x07060302u);
  hi.z = __builtin_amdgcn_perm(xh[5], xh[4], 0x07060302u);
  hi.w = __builtin_amdgcn_perm(xh[7], xh[6], 0x07060302u);
  lo.x = __builtin_amdgcn_perm(xl[1], xl[0], 0x07060302u);
  lo.y = __builtin_amdgcn_perm(xl[3], xl[2], 0x07060302u);
  lo.z = __builtin_amdgcn_perm(xl[5], xl[4], 0x07060302u);
  lo.w = __builtin_amdgcn_perm(xl[7], xl[6], 0x07060302u);
}

// LDS 16B-unit index for (column c, k-half kh) within one 16-k substep (r4-validated).
__device__ __forceinline__ int ldsu(int c, int kh) {
  return ((c << 1) | kh) ^ ((c >> 2) & 7);
}

// ---------------------------------------------------------------------------
// Kernel 1: per (chunk, batch): partial[c][d] = sum_{k in chunk} L[k][c]*R[k][d]
// 512 threads = 8 waves (2x4 grid of 64x32 tiles, 32x32x16 MFMA, 3-pass split).
// LDS: [set][substep][unit]; 64 KB total. Tile = 32 k-rows, two 16-k substeps.
// ---------------------------------------------------------------------------
__global__ __launch_bounds__(512, 2)
void bcnn_gemm_kernel(const float* __restrict__ L, const float* __restrict__ R) {
  __shared__ uint4 sAhi[2][2][256], sAlo[2][2][256];
  __shared__ uint4 sBhi[2][2][256], sBlo[2][2][256];

  const int chunk = blockIdx.x;      // 0..7
  const int b     = blockIdx.y;
  const int t     = threadIdx.x;
  const int l     = t & 63;
  const int w     = t >> 6;
  const int wr    = w >> 2;          // 0..1
  const int wc    = w & 3;           // 0..3
  const int lc    = l & 31;
  const int hh    = l >> 5;          // k-half selector within a substep

  // staging: thread owns column sc, k-rows sh*8 .. sh*8+7 of each 32-k tile
  const int sc  = t & 127;
  const int sh  = t >> 7;            // 0..3
  const int sub = sh >> 1;           // substep region 0/1
  const int wu  = ldsu(sc, sh & 1);

  const float* gL = L + ((size_t)b * XDIM + (size_t)chunk * KC + sh * 8) * CDIM + sc;
  const float* gR = R + ((size_t)b * XDIM + (size_t)chunk * KC + sh * 8) * CDIM + sc;

  // fragment units (per substep)
  const int cA0 = wr * 64 + lc;
  const int cA1 = cA0 + 32;
  const int dB  = wc * 32 + lc;
  const int uA0 = ldsu(cA0, hh);
  const int uA1 = ldsu(cA1, hh);
  const int uB  = ldsu(dB,  hh);

  f32x16 acc0 = {};
  f32x16 acc1 = {};

  float rlE[8], rrE[8], rlO[8], rrO[8];   // two static register-parity sets

#define LOADR(rl, rr, s)                                                        \
  do {                                                                          \
    const float* pL_ = gL + (size_t)(s) * BK * CDIM;                            \
    const float* pR_ = gR + (size_t)(s) * BK * CDIM;                            \
    _Pragma("unroll")                                                           \
    for (int i = 0; i < 8; ++i) { rl[i] = pL_[i * CDIM]; rr[i] = pR_[i * CDIM]; } \
  } while (0)

#define WRITE(rl, rr, set)                                                      \
  do {                                                                          \
    uint4 hi_, lo_;                                                             \
    split8(rl, hi_, lo_);                                                       \
    sAhi[set][sub][wu] = hi_; sAlo[set][sub][wu] = lo_;                         \
    split8(rr, hi_, lo_);                                                       \
    sBhi[set][sub][wu] = hi_; sBlo[set][sub][wu] = lo_;                         \
  } while (0)

#define COMPUTE(set)                                                            \
  do {                                                                          \
    _Pragma("unroll")                                                           \
    for (int ss = 0; ss < 2; ++ss) {                                            \
      bf16x8 ah0 = *(const bf16x8*)&sAhi[set][ss][uA0];                         \
      bf16x8 al0 = *(const bf16x8*)&sAlo[set][ss][uA0];                         \
      bf16x8 ah1 = *(const bf16x8*)&sAhi[set][ss][uA1];                         \
      bf16x8 al1 = *(const bf16x8*)&sAlo[set][ss][uA1];                         \
      bf16x8 bh  = *(const bf16x8*)&sBhi[set][ss][uB];                          \
      bf16x8 bl  = *(const bf16x8*)&sBlo[set][ss][uB];                          \
      acc0 = __builtin_amdgcn_mfma_f32_32x32x16_bf16(ah0, bh, acc0, 0, 0, 0);   \
      acc1 = __builtin_amdgcn_mfma_f32_32x32x16_bf16(ah1, bh, acc1, 0, 0, 0);   \
      acc0 = __builtin_amdgcn_mfma_f32_32x32x16_bf16(ah0, bl, acc0, 0, 0, 0);   \
      acc1 = __builtin_amdgcn_mfma_f32_32x32x16_bf16(ah1, bl, acc1, 0, 0, 0);   \
      acc0 = __builtin_amdgcn_mfma_f32_32x32x16_bf16(al0, bh, acc0, 0, 0, 0);   \
      acc1 = __builtin_amdgcn_mfma_f32_32x32x16_bf16(al1, bh, acc1, 0, 0, 0);   \
    }                                                                           \
  } while (0)

#define BAR()                                                                   \
  do {                                                                          \
    asm volatile("s_waitcnt lgkmcnt(0)" ::: "memory");                          \
    __builtin_amdgcn_s_barrier();                                               \
  } while (0)

  // prologue: tiles 0,1 in flight; write tile 0 (waits its regs; tile 1 stays live)
  LOADR(rlE, rrE, 0);
  LOADR(rlO, rrO, 1);
  WRITE(rlE, rrE, 0);
  BAR();

  // steady state, 2-unrolled for static register parity.
  // iter s: compute set s&1; issue tile s+2 into parity s&1; write tile s+1.
  for (int it = 0; it < 24; ++it) {
    const int s0 = 2 * it;
    // even iter
    LOADR(rlE, rrE, s0 + 2);
    COMPUTE(0);
    WRITE(rlO, rrO, 1);
    BAR();
    // odd iter
    if (s0 + 3 < NT) LOADR(rlO, rrO, s0 + 3);
    COMPUTE(1);
    WRITE(rlE, rrE, 0);
    BAR();
  }
  // final tile s = 48 (set 0)
  COMPUTE(0);

#undef LOADR
#undef WRITE
#undef COMPUTE
#undef BAR

  // C/D layout (HW-validated r1-r4): col = lane&31, row = (r&3)+8*(r>>2)+4*hh
  float* outp = g_part + (((size_t)chunk * BATCH + b) << 14);
#pragma unroll
  for (int r = 0; r < 16; ++r) {
    const int row = (r & 3) + ((r >> 2) << 3) + (hh << 2);
    outp[(size_t)(wr * 64 + row) * CDIM + (wc * 32 + lc)]      = acc0[r];
    outp[(size_t)(wr * 64 + 32 + row) * CDIM + (wc * 32 + lc)] = acc1[r];
  }
}

// ---------------------------------------------------------------------------
// Kernel 2a: sum NK partials, signed-sqrt, write sqrted, per-segment sumsq.
// ---------------------------------------------------------------------------
__global__ void bcnn_sqrt_kernel(float* __restrict__ out) {
  const int b   = blockIdx.y;
  const int seg = blockIdx.x;
  const int t   = threadIdx.x;
  const int idx = seg * 1024 + t * 4;

  float4 v = {0.f, 0.f, 0.f, 0.f};
#pragma unroll
  for (int ch = 0; ch < NK; ++ch) {
    const float4 p = *(const float4*)&g_part[(((size_t)ch * BATCH + b) << 14) + idx];
    v.x += p.x; v.y += p.y; v.z += p.z; v.w += p.w;
  }
  float4 sv;
  {
    float a;
    a = sqrtf(fabsf(v.x) + 1e-9f); sv.x = (v.x > 0.f) ? a : ((v.x < 0.f) ? -a : 0.f);
    a = sqrtf(fabsf(v.y) + 1e-9f); sv.y = (v.y > 0.f) ? a : ((v.y < 0.f) ? -a : 0.f);
    a = sqrtf(fabsf(v.z) + 1e-9f); sv.z = (v.z > 0.f) ? a : ((v.z < 0.f) ? -a : 0.f);
    a = sqrtf(fabsf(v.w) + 1e-9f); sv.w = (v.w > 0.f) ? a : ((v.w < 0.f) ? -a : 0.f);
  }
  *(float4*)&out[((size_t)b << 14) + idx] = sv;

  float ss = sv.x * sv.x + sv.y * sv.y + sv.z * sv.z + sv.w * sv.w;
#pragma unroll
  for (int o = 32; o > 0; o >>= 1) ss += __shfl_down(ss, o, 64);
  __shared__ float red[4];
  if ((t & 63) == 0) red[t >> 6] = ss;
  __syncthreads();
  if (t == 0) g_ssq[b * 16 + seg] = red[0] + red[1] + red[2] + red[3];
}

// ---------------------------------------------------------------------------
// Kernel 2b: scale by rsqrt(max(sumsq, 1e-12))
// ---------------------------------------------------------------------------
__global__ void bcnn_scale_kernel(float* __restrict__ out) {
  const int b   = blockIdx.y;
  const int seg = blockIdx.x;
  const int t   = threadIdx.x;

  float tot = 0.f;
#pragma unroll
  for (int i = 0; i < 16; ++i) tot += g_ssq[b * 16 + i];
  const float scale = rsqrtf(fmaxf(tot, 1e-12f));

  const size_t base = ((size_t)b << 14) + seg * 1024 + t * 4;
  float4 v = *(float4*)&out[base];
  v.x *= scale; v.y *= scale; v.z *= scale; v.w *= scale;
  *(float4*)&out[base] = v;
}

extern "C" void kernel_launch(void* const* d_in, const int* in_sizes, int n_in,
                              void* d_out, int out_size, void* d_ws, size_t ws_size,
                              hipStream_t stream) {
  const float* L = (const float*)d_in[0];
  const float* R = (const float*)d_in[1];
  float* out = (float*)d_out;

  dim3 g1(NK, BATCH);
  bcnn_gemm_kernel<<<g1, 512, 0, stream>>>(L, R);

  dim3 g2(16, BATCH);
  bcnn_sqrt_kernel<<<g2, 256, 0, stream>>>(out);
  bcnn_scale_kernel<<<g2, 256, 0, stream>>>(out);
}

// Round 6
// 87.756 us; speedup vs baseline: 1.2094x; 1.0539x over previous
//
#include <hip/hip_runtime.h>
#include <hip/hip_bf16.h>

// Bilinear CNN pooling: dotted[b,c,d] = sum_x L[b,x,c]*R[b,x,d]  (B=32, X=12544, C=128)
// then signed-sqrt + global L2-normalize per batch.
//
// Round 6: r5 + 3-tile register lookahead (load parity mod 3, LDS sets mod 2).
// WRITE consumes loads issued 2 iters earlier -> ~6400cy slack vs ~900cy HBM
// latency -> no per-iter stall at the vmcnt wait. 6-unrolled static loop.

#define NK      8             // K-chunks per batch
#define KC      1568          // 12544 / 8
#define BK      32            // K per tile
#define NT      49            // KC / BK
#define BATCH   32
#define CDIM    128
#define XDIM    12544

typedef __bf16 bf16x8 __attribute__((ext_vector_type(8)));
typedef float  f32x16 __attribute__((ext_vector_type(16)));

// 16 MB partial buffer + per-segment sumsq; fully rewritten before read each launch.
__device__ float g_part[(size_t)NK * BATCH * CDIM * CDIM];
__device__ float g_ssq[BATCH * 16];

// Split 8 f32 -> RNE-bf16 hi + trunc-bf16 lo, packed into uint4s (validated r1-r5).
__device__ __forceinline__ void split8(const float* f, uint4& hi, uint4& lo) {
  uint xh[8], xl[8];
#pragma unroll
  for (int i = 0; i < 8; ++i) {
    uint u = __float_as_uint(f[i]);
    uint r = u + 0x7FFFu + ((u >> 16) & 1u);        // RNE bf16 in top 16 bits
    xh[i] = r;
    float hif = __uint_as_float(r & 0xFFFF0000u);    // exact hi value
    xl[i] = __float_as_uint(f[i] - hif);             // exact residual, trunc on pack
  }
  hi.x = __builtin_amdgcn_perm(xh[1], xh[0], 0x07060302u);
  hi.y = __builtin_amdgcn_perm(xh[3], xh[2], 0x07060302u);
  hi.z = __builtin_amdgcn_perm(xh[5], xh[4], 0x07060302u);
  hi.w = __builtin_amdgcn_perm(xh[7], xh[6], 0x07060302u);
  lo.x = __builtin_amdgcn_perm(xl[1], xl[0], 0x07060302u);
  lo.y = __builtin_amdgcn_perm(xl[3], xl[2], 0x07060302u);
  lo.z = __builtin_amdgcn_perm(xl[5], xl[4], 0x07060302u);
  lo.w = __builtin_amdgcn_perm(xl[7], xl[6], 0x07060302u);
}

// LDS 16B-unit index for (column c, k-half kh) within one 16-k substep (r4/r5-validated).
__device__ __forceinline__ int ldsu(int c, int kh) {
  return ((c << 1) | kh) ^ ((c >> 2) & 7);
}

// ---------------------------------------------------------------------------
// Kernel 1: per (chunk, batch): partial[c][d] = sum_{k in chunk} L[k][c]*R[k][d]
// 512 threads = 8 waves (2x4 grid of 64x32 tiles, 32x32x16 MFMA, 3-pass split).
// LDS: [set][substep][unit]; 64 KB. Tile = 32 k-rows, two 16-k substeps.
// ---------------------------------------------------------------------------
__global__ __launch_bounds__(512, 2)
void bcnn_gemm_kernel(const float* __restrict__ L, const float* __restrict__ R) {
  __shared__ uint4 sAhi[2][2][256], sAlo[2][2][256];
  __shared__ uint4 sBhi[2][2][256], sBlo[2][2][256];

  const int chunk = blockIdx.x;      // 0..7
  const int b     = blockIdx.y;
  const int t     = threadIdx.x;
  const int l     = t & 63;
  const int w     = t >> 6;
  const int wr    = w >> 2;          // 0..1
  const int wc    = w & 3;           // 0..3
  const int lc    = l & 31;
  const int hh    = l >> 5;          // k-half selector within a substep

  // staging: thread owns column sc, k-rows sh*8 .. sh*8+7 of each 32-k tile
  const int sc  = t & 127;
  const int sh  = t >> 7;            // 0..3
  const int sub = sh >> 1;           // substep region 0/1
  const int wu  = ldsu(sc, sh & 1);

  const float* gL = L + ((size_t)b * XDIM + (size_t)chunk * KC + sh * 8) * CDIM + sc;
  const float* gR = R + ((size_t)b * XDIM + (size_t)chunk * KC + sh * 8) * CDIM + sc;

  // fragment units (per substep)
  const int cA0 = wr * 64 + lc;
  const int cA1 = cA0 + 32;
  const int dB  = wc * 32 + lc;
  const int uA0 = ldsu(cA0, hh);
  const int uA1 = ldsu(cA1, hh);
  const int uB  = ldsu(dB,  hh);

  f32x16 acc0 = {};
  f32x16 acc1 = {};

  // three static register-parity sets (tile s has parity s % 3)
  float rlA[8], rrA[8], rlB[8], rrB[8], rlC[8], rrC[8];

#define LOADR(rl, rr, s)                                                        \
  do {                                                                          \
    const float* pL_ = gL + (size_t)(s) * BK * CDIM;                            \
    const float* pR_ = gR + (size_t)(s) * BK * CDIM;                            \
    _Pragma("unroll")                                                           \
    for (int i = 0; i < 8; ++i) { rl[i] = pL_[i * CDIM]; rr[i] = pR_[i * CDIM]; } \
  } while (0)

#define WRITE(rl, rr, set)                                                      \
  do {                                                                          \
    uint4 hi_, lo_;                                                             \
    split8(rl, hi_, lo_);                                                       \
    sAhi[set][sub][wu] = hi_; sAlo[set][sub][wu] = lo_;                         \
    split8(rr, hi_, lo_);                                                       \
    sBhi[set][sub][wu] = hi_; sBlo[set][sub][wu] = lo_;                         \
  } while (0)

#define COMPUTE(set)                                                            \
  do {                                                                          \
    _Pragma("unroll")                                                           \
    for (int ss = 0; ss < 2; ++ss) {                                            \
      bf16x8 ah0 = *(const bf16x8*)&sAhi[set][ss][uA0];                         \
      bf16x8 al0 = *(const bf16x8*)&sAlo[set][ss][uA0];                         \
      bf16x8 ah1 = *(const bf16x8*)&sAhi[set][ss][uA1];                         \
      bf16x8 al1 = *(const bf16x8*)&sAlo[set][ss][uA1];                         \
      bf16x8 bh  = *(const bf16x8*)&sBhi[set][ss][uB];                          \
      bf16x8 bl  = *(const bf16x8*)&sBlo[set][ss][uB];                          \
      acc0 = __builtin_amdgcn_mfma_f32_32x32x16_bf16(ah0, bh, acc0, 0, 0, 0);   \
      acc1 = __builtin_amdgcn_mfma_f32_32x32x16_bf16(ah1, bh, acc1, 0, 0, 0);   \
      acc0 = __builtin_amdgcn_mfma_f32_32x32x16_bf16(ah0, bl, acc0, 0, 0, 0);   \
      acc1 = __builtin_amdgcn_mfma_f32_32x32x16_bf16(ah1, bl, acc1, 0, 0, 0);   \
      acc0 = __builtin_amdgcn_mfma_f32_32x32x16_bf16(al0, bh, acc0, 0, 0, 0);   \
      acc1 = __builtin_amdgcn_mfma_f32_32x32x16_bf16(al1, bh, acc1, 0, 0, 0);   \
    }                                                                           \
  } while (0)

#define BAR()                                                                   \
  do {                                                                          \
    asm volatile("s_waitcnt lgkmcnt(0)" ::: "memory");                          \
    __builtin_amdgcn_s_barrier();                                               \
  } while (0)

  // prologue: tiles 0,1,2 in flight; write tile 0 (waits only its own regs)
  LOADR(rlA, rrA, 0);
  LOADR(rlB, rrB, 1);
  LOADR(rlC, rrC, 2);
  WRITE(rlA, rrA, 0);
  BAR();

  // steady state: iter s -> COMPUTE(tile s, set s&1); issue tile s+3 into
  // parity (s+3)%3 = s%3; WRITE tile s+1 (loaded at iter s-2) into set (s+1)&1.
  // 6-unrolled (lcm(2,3)) for fully static parity/set names.
  for (int it = 0; it < 7; ++it) {
    const int s0 = 6 * it;
    /* s0+0 */ LOADR(rlA, rrA, s0 + 3); COMPUTE(0); WRITE(rlB, rrB, 1); BAR();
    /* s0+1 */ LOADR(rlB, rrB, s0 + 4); COMPUTE(1); WRITE(rlC, rrC, 0); BAR();
    /* s0+2 */ LOADR(rlC, rrC, s0 + 5); COMPUTE(0); WRITE(rlA, rrA, 1); BAR();
    /* s0+3 */ LOADR(rlA, rrA, s0 + 6); COMPUTE(1); WRITE(rlB, rrB, 0); BAR();
    /* s0+4 */ LOADR(rlB, rrB, s0 + 7); COMPUTE(0); WRITE(rlC, rrC, 1); BAR();
    /* s0+5 */ LOADR(rlC, rrC, s0 + 8); COMPUTE(1); WRITE(rlA, rrA, 0); BAR();
  }
  // peeled tail: s = 42..48 (loads stop at tile 48)
  /* s=42 */ LOADR(rlA, rrA, 45); COMPUTE(0); WRITE(rlB, rrB, 1); BAR();
  /* s=43 */ LOADR(rlB, rrB, 46); COMPUTE(1); WRITE(rlC, rrC, 0); BAR();
  /* s=44 */ LOADR(rlC, rrC, 47); COMPUTE(0); WRITE(rlA, rrA, 1); BAR();
  /* s=45 */ LOADR(rlA, rrA, 48); COMPUTE(1); WRITE(rlB, rrB, 0); BAR();
  /* s=46 */ COMPUTE(0); WRITE(rlC, rrC, 1); BAR();
  /* s=47 */ COMPUTE(1); WRITE(rlA, rrA, 0); BAR();
  /* s=48 */ COMPUTE(0);

#undef LOADR
#undef WRITE
#undef COMPUTE
#undef BAR

  // C/D layout (HW-validated r1-r5): col = lane&31, row = (r&3)+8*(r>>2)+4*hh
  float* outp = g_part + (((size_t)chunk * BATCH + b) << 14);
#pragma unroll
  for (int r = 0; r < 16; ++r) {
    const int row = (r & 3) + ((r >> 2) << 3) + (hh << 2);
    outp[(size_t)(wr * 64 + row) * CDIM + (wc * 32 + lc)]      = acc0[r];
    outp[(size_t)(wr * 64 + 32 + row) * CDIM + (wc * 32 + lc)] = acc1[r];
  }
}

// ---------------------------------------------------------------------------
// Kernel 2a: sum NK partials, signed-sqrt, write sqrted, per-segment sumsq.
// ---------------------------------------------------------------------------
__global__ void bcnn_sqrt_kernel(float* __restrict__ out) {
  const int b   = blockIdx.y;
  const int seg = blockIdx.x;
  const int t   = threadIdx.x;
  const int idx = seg * 1024 + t * 4;

  float4 v = {0.f, 0.f, 0.f, 0.f};
#pragma unroll
  for (int ch = 0; ch < NK; ++ch) {
    const float4 p = *(const float4*)&g_part[(((size_t)ch * BATCH + b) << 14) + idx];
    v.x += p.x; v.y += p.y; v.z += p.z; v.w += p.w;
  }
  float4 sv;
  {
    float a;
    a = sqrtf(fabsf(v.x) + 1e-9f); sv.x = (v.x > 0.f) ? a : ((v.x < 0.f) ? -a : 0.f);
    a = sqrtf(fabsf(v.y) + 1e-9f); sv.y = (v.y > 0.f) ? a : ((v.y < 0.f) ? -a : 0.f);
    a = sqrtf(fabsf(v.z) + 1e-9f); sv.z = (v.z > 0.f) ? a : ((v.z < 0.f) ? -a : 0.f);
    a = sqrtf(fabsf(v.w) + 1e-9f); sv.w = (v.w > 0.f) ? a : ((v.w < 0.f) ? -a : 0.f);
  }
  *(float4*)&out[((size_t)b << 14) + idx] = sv;

  float ss = sv.x * sv.x + sv.y * sv.y + sv.z * sv.z + sv.w * sv.w;
#pragma unroll
  for (int o = 32; o > 0; o >>= 1) ss += __shfl_down(ss, o, 64);
  __shared__ float red[4];
  if ((t & 63) == 0) red[t >> 6] = ss;
  __syncthreads();
  if (t == 0) g_ssq[b * 16 + seg] = red[0] + red[1] + red[2] + red[3];
}

// ---------------------------------------------------------------------------
// Kernel 2b: scale by rsqrt(max(sumsq, 1e-12))
// ---------------------------------------------------------------------------
__global__ void bcnn_scale_kernel(float* __restrict__ out) {
  const int b   = blockIdx.y;
  const int seg = blockIdx.x;
  const int t   = threadIdx.x;

  float tot = 0.f;
#pragma unroll
  for (int i = 0; i < 16; ++i) tot += g_ssq[b * 16 + i];
  const float scale = rsqrtf(fmaxf(tot, 1e-12f));

  const size_t base = ((size_t)b << 14) + seg * 1024 + t * 4;
  float4 v = *(float4*)&out[base];
  v.x *= scale; v.y *= scale; v.z *= scale; v.w *= scale;
  *(float4*)&out[base] = v;
}

extern "C" void kernel_launch(void* const* d_in, const int* in_sizes, int n_in,
                              void* d_out, int out_size, void* d_ws, size_t ws_size,
                              hipStream_t stream) {
  const float* L = (const float*)d_in[0];
  const float* R = (const float*)d_in[1];
  float* out = (float*)d_out;

  dim3 g1(NK, BATCH);
  bcnn_gemm_kernel<<<g1, 512, 0, stream>>>(L, R);

  dim3 g2(16, BATCH);
  bcnn_sqrt_kernel<<<g2, 256, 0, stream>>>(out);
  bcnn_scale_kernel<<<g2, 256, 0, stream>>>(out);
}